// Round 1
// baseline (505.025 us; speedup 1.0000x reference)
//
#include <hip/hip_runtime.h>

// Problem dims (fixed by setup_inputs): B=1, C=32, H=W=1024, fp32.
constexpr int C  = 32;
constexpr int H  = 1024;
constexpr int W  = 1024;
constexpr int HW = H * W;

__global__ __launch_bounds__(256) void stn_warp_kernel(
    const float* __restrict__ flow,  // [2, H, W]
    const float* __restrict__ x,     // [C, H, W]
    float* __restrict__ out)         // [C, H, W]
{
    const int tid = blockIdx.x * blockDim.x + threadIdx.x;
    if (tid >= HW) return;

    const int w = tid & (W - 1);
    const int h = tid >> 10;   // log2(W)

    const float fx = flow[tid];        // flow[0,h,w]
    const float fy = flow[HW + tid];   // flow[1,h,w]

    // Mirror reference arithmetic order exactly (fp32):
    // gx = (flow + base)/(W-1)*2 - 1 ; ix = ((gx+1)*W - 1)*0.5
    const float gx = (fx + (float)w) / (float)(W - 1) * 2.0f - 1.0f;
    const float gy = (fy + (float)h) / (float)(H - 1) * 2.0f - 1.0f;
    const float ix = ((gx + 1.0f) * (float)W - 1.0f) * 0.5f;
    const float iy = ((gy + 1.0f) * (float)H - 1.0f) * 0.5f;

    const float x0f = floorf(ix);
    const float y0f = floorf(iy);
    const float wx1 = ix - x0f;
    const float wy1 = iy - y0f;
    const float wx0 = 1.0f - wx1;
    const float wy0 = 1.0f - wy1;

    const int x0 = (int)x0f;
    const int y0 = (int)y0f;
    const int x1 = x0 + 1;
    const int y1 = y0 + 1;

    const float vx0 = (x0 >= 0 && x0 < W) ? 1.0f : 0.0f;
    const float vx1 = (x1 >= 0 && x1 < W) ? 1.0f : 0.0f;
    const float vy0 = (y0 >= 0 && y0 < H) ? 1.0f : 0.0f;
    const float vy1 = (y1 >= 0 && y1 < H) ? 1.0f : 0.0f;

    // Zero-padding folded into weights.
    const float w00 = wx0 * wy0 * vx0 * vy0;
    const float w10 = wx1 * wy0 * vx1 * vy0;
    const float w01 = wx0 * wy1 * vx0 * vy1;
    const float w11 = wx1 * wy1 * vx1 * vy1;

    const int xc0 = min(max(x0, 0), W - 1);
    const int xc1 = min(max(x1, 0), W - 1);
    const int yc0 = min(max(y0, 0), H - 1);
    const int yc1 = min(max(y1, 0), H - 1);

    const int o00 = yc0 * W + xc0;
    const int o10 = yc0 * W + xc1;
    const int o01 = yc1 * W + xc0;
    const int o11 = yc1 * W + xc1;

#pragma unroll
    for (int c = 0; c < C; ++c) {
        const float* __restrict__ xc = x + c * HW;
        const float v = xc[o00] * w00 + xc[o10] * w10
                      + xc[o01] * w01 + xc[o11] * w11;
        out[c * HW + tid] = v;
    }
}

extern "C" void kernel_launch(void* const* d_in, const int* in_sizes, int n_in,
                              void* d_out, int out_size, void* d_ws, size_t ws_size,
                              hipStream_t stream) {
    const float* flow = (const float*)d_in[0];  // [1,2,1024,1024]
    const float* x    = (const float*)d_in[1];  // [1,32,1024,1024]
    float* out        = (float*)d_out;          // [1,32,1024,1024]

    const int threads = 256;
    const int blocks  = (HW + threads - 1) / threads;
    stn_warp_kernel<<<blocks, threads, 0, stream>>>(flow, x, out);
}

// Round 2
// 373.616 us; speedup vs baseline: 1.3517x; 1.3517x over previous
//
#include <hip/hip_runtime.h>

// Problem dims (fixed by setup_inputs): B=1, C=32, H=W=1024, fp32.
constexpr int C  = 32;
constexpr int H  = 1024;
constexpr int W  = 1024;
constexpr int HW = H * W;

// ---------------------------------------------------------------------------
// Pass 1: transpose x [C,H,W] -> xp [H*W][C] (pixel-major, 128 B per pixel)
// Block = 256 threads handles 64 consecutive pixels for all 32 channels.
// ---------------------------------------------------------------------------
__global__ __launch_bounds__(256) void transpose_kernel(
    const float* __restrict__ x, float* __restrict__ xp)
{
    __shared__ float lds[64 * 33];   // +1 pad: LDS write is (pl + c) % 32 -> 2-way max (free)
    const int p0 = blockIdx.x * 64;
    const int t  = threadIdx.x;

    // Load: each wave reads one channel-row of 64 consecutive pixels (256 B coalesced).
    const int pl = t & 63;
    const int cg = t >> 6;           // 0..3
#pragma unroll
    for (int i = 0; i < 8; ++i) {
        const int c = i * 4 + cg;
        lds[pl * 33 + c] = x[(size_t)c * HW + p0 + pl];
    }
    __syncthreads();

    // Store: thread t writes 8 channels (32 B) of one pixel; block writes a
    // contiguous 8 KB chunk of xp (full-line utilization).
    const int p = t >> 2;
    const int q = t & 3;
    float4 a, b;
    a.x = lds[p * 33 + q * 8 + 0];
    a.y = lds[p * 33 + q * 8 + 1];
    a.z = lds[p * 33 + q * 8 + 2];
    a.w = lds[p * 33 + q * 8 + 3];
    b.x = lds[p * 33 + q * 8 + 4];
    b.y = lds[p * 33 + q * 8 + 5];
    b.z = lds[p * 33 + q * 8 + 6];
    b.w = lds[p * 33 + q * 8 + 7];
    float4* dst = (float4*)(xp + (size_t)(p0 + p) * C + q * 8);
    dst[0] = a;
    dst[1] = b;
}

// ---------------------------------------------------------------------------
// Pass 2: bilinear gather in pixel-major layout. Each corner read is 8
// contiguous float4 lane-loads (128 B fully used). Output stores coalesced.
// ---------------------------------------------------------------------------
__global__ __launch_bounds__(256) void gather_kernel(
    const float* __restrict__ flow,
    const float* __restrict__ xp,
    float* __restrict__ out)
{
    const int tid = blockIdx.x * blockDim.x + threadIdx.x;
    if (tid >= HW) return;

    const int w = tid & (W - 1);
    const int h = tid >> 10;

    const float fx = flow[tid];
    const float fy = flow[HW + tid];

    // Mirror reference arithmetic order exactly (fp32).
    const float gx = (fx + (float)w) / (float)(W - 1) * 2.0f - 1.0f;
    const float gy = (fy + (float)h) / (float)(H - 1) * 2.0f - 1.0f;
    const float ix = ((gx + 1.0f) * (float)W - 1.0f) * 0.5f;
    const float iy = ((gy + 1.0f) * (float)H - 1.0f) * 0.5f;

    const float x0f = floorf(ix);
    const float y0f = floorf(iy);
    const float wx1 = ix - x0f;
    const float wy1 = iy - y0f;
    const float wx0 = 1.0f - wx1;
    const float wy0 = 1.0f - wy1;

    const int x0 = (int)x0f;
    const int y0 = (int)y0f;
    const int x1 = x0 + 1;
    const int y1 = y0 + 1;

    const float vx0 = (x0 >= 0 && x0 < W) ? 1.0f : 0.0f;
    const float vx1 = (x1 >= 0 && x1 < W) ? 1.0f : 0.0f;
    const float vy0 = (y0 >= 0 && y0 < H) ? 1.0f : 0.0f;
    const float vy1 = (y1 >= 0 && y1 < H) ? 1.0f : 0.0f;

    const float w00 = wx0 * wy0 * vx0 * vy0;
    const float w10 = wx1 * wy0 * vx1 * vy0;
    const float w01 = wx0 * wy1 * vx0 * vy1;
    const float w11 = wx1 * wy1 * vx1 * vy1;

    const int xc0 = min(max(x0, 0), W - 1);
    const int xc1 = min(max(x1, 0), W - 1);
    const int yc0 = min(max(y0, 0), H - 1);
    const int yc1 = min(max(y1, 0), H - 1);

    // float4-unit base offsets into xp (8 float4 per pixel).
    const int b00 = (yc0 * W + xc0) * 8;
    const int b10 = (yc0 * W + xc1) * 8;
    const int b01 = (yc1 * W + xc0) * 8;
    const int b11 = (yc1 * W + xc1) * 8;

    const float4* __restrict__ xq = (const float4*)xp;

    float4 acc[8];
    {
        float4 v0[8], v1[8];
#pragma unroll
        for (int j = 0; j < 8; ++j) v0[j] = xq[b00 + j];
#pragma unroll
        for (int j = 0; j < 8; ++j) v1[j] = xq[b10 + j];
#pragma unroll
        for (int j = 0; j < 8; ++j) {
            acc[j].x = v0[j].x * w00 + v1[j].x * w10;
            acc[j].y = v0[j].y * w00 + v1[j].y * w10;
            acc[j].z = v0[j].z * w00 + v1[j].z * w10;
            acc[j].w = v0[j].w * w00 + v1[j].w * w10;
        }
    }
    {
        float4 v0[8], v1[8];
#pragma unroll
        for (int j = 0; j < 8; ++j) v0[j] = xq[b01 + j];
#pragma unroll
        for (int j = 0; j < 8; ++j) v1[j] = xq[b11 + j];
#pragma unroll
        for (int j = 0; j < 8; ++j) {
            acc[j].x += v0[j].x * w01 + v1[j].x * w11;
            acc[j].y += v0[j].y * w01 + v1[j].y * w11;
            acc[j].z += v0[j].z * w01 + v1[j].z * w11;
            acc[j].w += v0[j].w * w01 + v1[j].w * w11;
        }
    }

    // Coalesced stores: consecutive lanes -> consecutive addresses per channel.
#pragma unroll
    for (int j = 0; j < 8; ++j) {
        out[(size_t)(j * 4 + 0) * HW + tid] = acc[j].x;
        out[(size_t)(j * 4 + 1) * HW + tid] = acc[j].y;
        out[(size_t)(j * 4 + 2) * HW + tid] = acc[j].z;
        out[(size_t)(j * 4 + 3) * HW + tid] = acc[j].w;
    }
}

// ---------------------------------------------------------------------------
// Fallback (round-1 kernel) if workspace is too small for the transposed copy.
// ---------------------------------------------------------------------------
__global__ __launch_bounds__(256) void stn_warp_fallback(
    const float* __restrict__ flow,
    const float* __restrict__ x,
    float* __restrict__ out)
{
    const int tid = blockIdx.x * blockDim.x + threadIdx.x;
    if (tid >= HW) return;

    const int w = tid & (W - 1);
    const int h = tid >> 10;

    const float fx = flow[tid];
    const float fy = flow[HW + tid];

    const float gx = (fx + (float)w) / (float)(W - 1) * 2.0f - 1.0f;
    const float gy = (fy + (float)h) / (float)(H - 1) * 2.0f - 1.0f;
    const float ix = ((gx + 1.0f) * (float)W - 1.0f) * 0.5f;
    const float iy = ((gy + 1.0f) * (float)H - 1.0f) * 0.5f;

    const float x0f = floorf(ix);
    const float y0f = floorf(iy);
    const float wx1 = ix - x0f;
    const float wy1 = iy - y0f;
    const float wx0 = 1.0f - wx1;
    const float wy0 = 1.0f - wy1;

    const int x0 = (int)x0f;
    const int y0 = (int)y0f;
    const int x1 = x0 + 1;
    const int y1 = y0 + 1;

    const float vx0 = (x0 >= 0 && x0 < W) ? 1.0f : 0.0f;
    const float vx1 = (x1 >= 0 && x1 < W) ? 1.0f : 0.0f;
    const float vy0 = (y0 >= 0 && y0 < H) ? 1.0f : 0.0f;
    const float vy1 = (y1 >= 0 && y1 < H) ? 1.0f : 0.0f;

    const float w00 = wx0 * wy0 * vx0 * vy0;
    const float w10 = wx1 * wy0 * vx1 * vy0;
    const float w01 = wx0 * wy1 * vx0 * vy1;
    const float w11 = wx1 * wy1 * vx1 * vy1;

    const int xc0 = min(max(x0, 0), W - 1);
    const int xc1 = min(max(x1, 0), W - 1);
    const int yc0 = min(max(y0, 0), H - 1);
    const int yc1 = min(max(y1, 0), H - 1);

    const int o00 = yc0 * W + xc0;
    const int o10 = yc0 * W + xc1;
    const int o01 = yc1 * W + xc0;
    const int o11 = yc1 * W + xc1;

#pragma unroll
    for (int c = 0; c < C; ++c) {
        const float* __restrict__ xc = x + c * HW;
        const float v = xc[o00] * w00 + xc[o10] * w10
                      + xc[o01] * w01 + xc[o11] * w11;
        out[c * HW + tid] = v;
    }
}

extern "C" void kernel_launch(void* const* d_in, const int* in_sizes, int n_in,
                              void* d_out, int out_size, void* d_ws, size_t ws_size,
                              hipStream_t stream) {
    const float* flow = (const float*)d_in[0];  // [1,2,1024,1024]
    const float* x    = (const float*)d_in[1];  // [1,32,1024,1024]
    float* out        = (float*)d_out;          // [1,32,1024,1024]

    const size_t need = (size_t)HW * C * sizeof(float);  // 128 MB
    if (ws_size >= need) {
        float* xp = (float*)d_ws;
        transpose_kernel<<<HW / 64, 256, 0, stream>>>(x, xp);
        gather_kernel<<<HW / 256, 256, 0, stream>>>(flow, xp, out);
    } else {
        stn_warp_fallback<<<HW / 256, 256, 0, stream>>>(flow, x, out);
    }
}

// Round 3
// 337.292 us; speedup vs baseline: 1.4973x; 1.1077x over previous
//
#include <hip/hip_runtime.h>

// Problem dims (fixed by setup_inputs): B=1, C=32, H=W=1024, fp32.
constexpr int C  = 32;
constexpr int H  = 1024;
constexpr int W  = 1024;
constexpr int HW = H * W;

// ---------------------------------------------------------------------------
// Pass 1: transpose x [C,H,W] -> xp [H*W][C] (pixel-major, 128 B per pixel).
// 256 pixels per block. float4 loads (1 KB/wave), conflict-free b128 LDS
// writes (channel-major LDS), coalesced float4 stores (1 KB/wave).
// ---------------------------------------------------------------------------
constexpr int TP_PX   = 256;
constexpr int LDS_PAD = 260;   // 256 + 4: keeps 16B alignment, breaks bank aliasing

__global__ __launch_bounds__(256) void transpose_kernel(
    const float* __restrict__ x, float* __restrict__ xp)
{
    __shared__ float lds[C * LDS_PAD];   // 33.3 KB
    const int p0 = blockIdx.x * TP_PX;
    const int t  = threadIdx.x;
    const int pl = t & 63;     // float4 index within 256-px tile (per wave)
    const int cg = t >> 6;     // wave id -> channel subgroup

    const float4* __restrict__ x4 = (const float4*)x;

    // Batch all 8 global loads first (8 outstanding 16B loads per lane).
    float4 v[8];
#pragma unroll
    for (int i = 0; i < 8; ++i) {
        const int c = i * 4 + cg;
        v[i] = x4[(size_t)c * (HW / 4) + (p0 >> 2) + pl];
    }
    __builtin_amdgcn_sched_barrier(0);   // keep loads hoisted above LDS writes

    // Channel-major LDS: b128 write at float-offset c*PAD + 4*pl — lanes write
    // sequential 16B chunks => conflict-free.
#pragma unroll
    for (int i = 0; i < 8; ++i) {
        const int c = i * 4 + cg;
        *(float4*)&lds[c * LDS_PAD + pl * 4] = v[i];
    }
    __syncthreads();

    // Store: flat float4 index f = m*256 + t over the block's 2048-float4
    // output region => consecutive lanes write consecutive float4s (coalesced).
    float4* __restrict__ xp4 = (float4*)xp + (size_t)p0 * 8;
#pragma unroll
    for (int m = 0; m < 8; ++m) {
        const int f  = m * 256 + t;
        const int px = f >> 3;        // pixel within tile
        const int j  = f & 7;         // float4 within pixel (channels j*4..j*4+3)
        float4 o;
        o.x = lds[(j * 4 + 0) * LDS_PAD + px];
        o.y = lds[(j * 4 + 1) * LDS_PAD + px];
        o.z = lds[(j * 4 + 2) * LDS_PAD + px];
        o.w = lds[(j * 4 + 3) * LDS_PAD + px];
        xp4[f] = o;
    }
}

// ---------------------------------------------------------------------------
// Pass 2: bilinear gather in pixel-major layout. Two phases of 16 batched
// float4 loads (sched_barrier keeps them outstanding together).
// ---------------------------------------------------------------------------
__global__ __launch_bounds__(256) void gather_kernel(
    const float* __restrict__ flow,
    const float* __restrict__ xp,
    float* __restrict__ out)
{
    const int tid = blockIdx.x * blockDim.x + threadIdx.x;
    if (tid >= HW) return;

    const int w = tid & (W - 1);
    const int h = tid >> 10;

    const float fx = flow[tid];
    const float fy = flow[HW + tid];

    // Mirror reference arithmetic order exactly (fp32).
    const float gx = (fx + (float)w) / (float)(W - 1) * 2.0f - 1.0f;
    const float gy = (fy + (float)h) / (float)(H - 1) * 2.0f - 1.0f;
    const float ix = ((gx + 1.0f) * (float)W - 1.0f) * 0.5f;
    const float iy = ((gy + 1.0f) * (float)H - 1.0f) * 0.5f;

    const float x0f = floorf(ix);
    const float y0f = floorf(iy);
    const float wx1 = ix - x0f;
    const float wy1 = iy - y0f;
    const float wx0 = 1.0f - wx1;
    const float wy0 = 1.0f - wy1;

    const int x0 = (int)x0f;
    const int y0 = (int)y0f;
    const int x1 = x0 + 1;
    const int y1 = y0 + 1;

    const float vx0 = (x0 >= 0 && x0 < W) ? 1.0f : 0.0f;
    const float vx1 = (x1 >= 0 && x1 < W) ? 1.0f : 0.0f;
    const float vy0 = (y0 >= 0 && y0 < H) ? 1.0f : 0.0f;
    const float vy1 = (y1 >= 0 && y1 < H) ? 1.0f : 0.0f;

    const float w00 = wx0 * wy0 * vx0 * vy0;
    const float w10 = wx1 * wy0 * vx1 * vy0;
    const float w01 = wx0 * wy1 * vx0 * vy1;
    const float w11 = wx1 * wy1 * vx1 * vy1;

    const int xc0 = min(max(x0, 0), W - 1);
    const int xc1 = min(max(x1, 0), W - 1);
    const int yc0 = min(max(y0, 0), H - 1);
    const int yc1 = min(max(y1, 0), H - 1);

    const int b00 = (yc0 * W + xc0) * 8;
    const int b10 = (yc0 * W + xc1) * 8;
    const int b01 = (yc1 * W + xc0) * 8;
    const int b11 = (yc1 * W + xc1) * 8;

    const float4* __restrict__ xq = (const float4*)xp;

    float4 acc[8];

    // Phase 1: corners (x0,y0) and (x1,y0) — 16 loads in flight.
    {
        float4 va[8], vb[8];
#pragma unroll
        for (int j = 0; j < 8; ++j) va[j] = xq[b00 + j];
#pragma unroll
        for (int j = 0; j < 8; ++j) vb[j] = xq[b10 + j];
        __builtin_amdgcn_sched_barrier(0);
#pragma unroll
        for (int j = 0; j < 8; ++j) {
            acc[j].x = va[j].x * w00 + vb[j].x * w10;
            acc[j].y = va[j].y * w00 + vb[j].y * w10;
            acc[j].z = va[j].z * w00 + vb[j].z * w10;
            acc[j].w = va[j].w * w00 + vb[j].w * w10;
        }
    }
    // Phase 2: corners (x0,y1) and (x1,y1).
    {
        float4 va[8], vb[8];
#pragma unroll
        for (int j = 0; j < 8; ++j) va[j] = xq[b01 + j];
#pragma unroll
        for (int j = 0; j < 8; ++j) vb[j] = xq[b11 + j];
        __builtin_amdgcn_sched_barrier(0);
#pragma unroll
        for (int j = 0; j < 8; ++j) {
            acc[j].x += va[j].x * w01 + vb[j].x * w11;
            acc[j].y += va[j].y * w01 + vb[j].y * w11;
            acc[j].z += va[j].z * w01 + vb[j].z * w11;
            acc[j].w += va[j].w * w01 + vb[j].w * w11;
        }
    }

    // Coalesced per-channel stores (256 B per wave-instr).
#pragma unroll
    for (int j = 0; j < 8; ++j) {
        out[(size_t)(j * 4 + 0) * HW + tid] = acc[j].x;
        out[(size_t)(j * 4 + 1) * HW + tid] = acc[j].y;
        out[(size_t)(j * 4 + 2) * HW + tid] = acc[j].z;
        out[(size_t)(j * 4 + 3) * HW + tid] = acc[j].w;
    }
}

// ---------------------------------------------------------------------------
// Fallback (round-1 kernel) if workspace is too small for the transposed copy.
// ---------------------------------------------------------------------------
__global__ __launch_bounds__(256) void stn_warp_fallback(
    const float* __restrict__ flow,
    const float* __restrict__ x,
    float* __restrict__ out)
{
    const int tid = blockIdx.x * blockDim.x + threadIdx.x;
    if (tid >= HW) return;

    const int w = tid & (W - 1);
    const int h = tid >> 10;

    const float fx = flow[tid];
    const float fy = flow[HW + tid];

    const float gx = (fx + (float)w) / (float)(W - 1) * 2.0f - 1.0f;
    const float gy = (fy + (float)h) / (float)(H - 1) * 2.0f - 1.0f;
    const float ix = ((gx + 1.0f) * (float)W - 1.0f) * 0.5f;
    const float iy = ((gy + 1.0f) * (float)H - 1.0f) * 0.5f;

    const float x0f = floorf(ix);
    const float y0f = floorf(iy);
    const float wx1 = ix - x0f;
    const float wy1 = iy - y0f;
    const float wx0 = 1.0f - wx1;
    const float wy0 = 1.0f - wy1;

    const int x0 = (int)x0f;
    const int y0 = (int)y0f;
    const int x1 = x0 + 1;
    const int y1 = y0 + 1;

    const float vx0 = (x0 >= 0 && x0 < W) ? 1.0f : 0.0f;
    const float vx1 = (x1 >= 0 && x1 < W) ? 1.0f : 0.0f;
    const float vy0 = (y0 >= 0 && y0 < H) ? 1.0f : 0.0f;
    const float vy1 = (y1 >= 0 && y1 < H) ? 1.0f : 0.0f;

    const float w00 = wx0 * wy0 * vx0 * vy0;
    const float w10 = wx1 * wy0 * vx1 * vy0;
    const float w01 = wx0 * wy1 * vx0 * vy1;
    const float w11 = wx1 * wy1 * vx1 * vy1;

    const int xc0 = min(max(x0, 0), W - 1);
    const int xc1 = min(max(x1, 0), W - 1);
    const int yc0 = min(max(y0, 0), H - 1);
    const int yc1 = min(max(y1, 0), H - 1);

    const int o00 = yc0 * W + xc0;
    const int o10 = yc0 * W + xc1;
    const int o01 = yc1 * W + xc0;
    const int o11 = yc1 * W + xc1;

#pragma unroll
    for (int c = 0; c < C; ++c) {
        const float* __restrict__ xc = x + c * HW;
        const float v = xc[o00] * w00 + xc[o10] * w10
                      + xc[o01] * w01 + xc[o11] * w11;
        out[c * HW + tid] = v;
    }
}

extern "C" void kernel_launch(void* const* d_in, const int* in_sizes, int n_in,
                              void* d_out, int out_size, void* d_ws, size_t ws_size,
                              hipStream_t stream) {
    const float* flow = (const float*)d_in[0];  // [1,2,1024,1024]
    const float* x    = (const float*)d_in[1];  // [1,32,1024,1024]
    float* out        = (float*)d_out;          // [1,32,1024,1024]

    const size_t need = (size_t)HW * C * sizeof(float);  // 128 MB
    if (ws_size >= need) {
        float* xp = (float*)d_ws;
        transpose_kernel<<<HW / TP_PX, 256, 0, stream>>>(x, xp);
        gather_kernel<<<HW / 256, 256, 0, stream>>>(flow, xp, out);
    } else {
        stn_warp_fallback<<<HW / 256, 256, 0, stream>>>(flow, x, out);
    }
}